// Round 1
// baseline (570.777 us; speedup 1.0000x reference)
//
#include <hip/hip_runtime.h>
#include <math.h>

// Problem constants (x: [8192, 512] fp32, K=5, eps=1e-8, scalar fp32 loss)
#define NROWS 8192
#define DIM   512
#define KNN   5
#define EPSV  1e-8f

// GEMM tiling: 128x128 block tile, BK=32, 4 waves (2x2), each wave 4x4 of 16x16x32 MFMA
#define BM 128
#define BN 128
#define BK 32
#define NSPLIT 8               // j-range splits per row-block (parallelism: 64*8=512 blocks)
#define JT_PER_SPLIT ((NROWS / BN) / NSPLIT)   // 8

typedef __attribute__((ext_vector_type(8))) _Float16 f16x8;
typedef __attribute__((ext_vector_type(4))) float    f32x4;

__device__ __forceinline__ void top5_insert(float v, float& t0, float& t1,
                                            float& t2, float& t3, float& t4) {
    // maintain t0 >= t1 >= t2 >= t3 >= t4
    if (v > t4) {
        if (v > t2) {
            if (v > t1) {
                if (v > t0) { t4 = t3; t3 = t2; t2 = t1; t1 = t0; t0 = v; }
                else        { t4 = t3; t3 = t2; t2 = t1; t1 = v; }
            } else          { t4 = t3; t3 = t2; t2 = v; }
        } else {
            if (v > t3)     { t4 = t3; t3 = v; }
            else            { t4 = v; }
        }
    }
}

// ---------------------------------------------------------------------------
// Kernel 1: row-normalize x (fp32) -> xn (f16). One block per row.
// ---------------------------------------------------------------------------
__global__ __launch_bounds__(256) void norm_kernel(const float* __restrict__ x,
                                                   _Float16* __restrict__ xnh) {
    const int row = blockIdx.x;
    const int t   = threadIdx.x;
    const float* xr = x + (size_t)row * DIM;
    float v0 = xr[t];
    float v1 = xr[t + 256];
    float s = v0 * v0 + v1 * v1;
    #pragma unroll
    for (int off = 32; off > 0; off >>= 1) s += __shfl_down(s, off, 64);
    __shared__ float wsum[4];
    __shared__ float inv_s;
    const int lane = t & 63, wv = t >> 6;
    if (lane == 0) wsum[wv] = s;
    __syncthreads();
    if (t == 0) {
        float tot = wsum[0] + wsum[1] + wsum[2] + wsum[3];
        inv_s = 1.0f / sqrtf(tot);
    }
    __syncthreads();
    const float inv = inv_s;
    _Float16* o = xnh + (size_t)row * DIM;
    o[t]       = (_Float16)(v0 * inv);
    o[t + 256] = (_Float16)(v1 * inv);
}

// ---------------------------------------------------------------------------
// Kernel 2: fused Gram-matrix tile GEMM + per-row running top-5 of dots.
// Block = 256 threads (4 waves). blockIdx -> (rowblk 0..63, split 0..7).
// Each block: rows [rowblk*128, +128), cols [split*1024, +1024) in 8 j-tiles.
// Writes per-(row,split) top-5 dot values to `part`.
// ---------------------------------------------------------------------------
__global__ __launch_bounds__(256) void dots_top5_kernel(const _Float16* __restrict__ xnh,
                                                        float* __restrict__ part) {
    // LDS: 8 KB + 8 KB staging, 32.5 KB C spill (stride 65 pads away conflicts)
    __shared__ __align__(16) _Float16 As[BM * BK];
    __shared__ __align__(16) _Float16 Bs[BN * BK];
    __shared__ __align__(16) float    Cs[BM * 65];   // 128 rows x 64 cols (one half), +1 pad

    const int tid    = threadIdx.x;
    const int lane   = tid & 63;
    const int wv     = tid >> 6;
    const int wm     = wv >> 1;          // wave row half (0..1)
    const int wn     = wv & 1;           // wave col half (0..1)
    const int m_lane = lane & 15;        // MFMA: m (A) / n (B) / col (C)
    const int quad   = lane >> 4;        // MFMA: k-chunk (A,B) / row-group (C)

    const int rowblk = blockIdx.x >> 3;  // 0..63
    const int split  = blockIdx.x & 7;   // 0..7
    const int i0     = rowblk * BM;

    // per-row running top-5 (threads 0..127 own one row each)
    float t0 = -2.f, t1 = -2.f, t2 = -2.f, t3 = -2.f, t4 = -2.f;

    for (int jj = 0; jj < JT_PER_SPLIT; ++jj) {
        const int jt = split * JT_PER_SPLIT + jj;
        const int j0 = jt * BN;

        f32x4 acc[4][4];
        #pragma unroll
        for (int m = 0; m < 4; ++m)
            #pragma unroll
            for (int n = 0; n < 4; ++n)
                acc[m][n] = (f32x4){0.f, 0.f, 0.f, 0.f};

        for (int ks = 0; ks < DIM / BK; ++ks) {
            const int k0 = ks * BK;
            // stage A,B tiles: 512 x 16B segments each; 2 per thread each.
            // seg s: row = s>>2, kseg = s&3 (4 x 8-halfs per 32-wide row)
            #pragma unroll
            for (int q = 0; q < 2; ++q) {
                const int s  = tid + q * 256;
                const int r  = s >> 2;
                const int kk = s & 3;
                const uint4 av = *(const uint4*)(xnh + (size_t)(i0 + r) * DIM + k0 + kk * 8);
                *(uint4*)(As + s * 8) = av;
                const uint4 bv = *(const uint4*)(xnh + (size_t)(j0 + r) * DIM + k0 + kk * 8);
                *(uint4*)(Bs + s * 8) = bv;
            }
            __syncthreads();

            f16x8 af[4], bf[4];
            #pragma unroll
            for (int m = 0; m < 4; ++m)
                af[m] = *(const f16x8*)(As + (wm * 64 + m * 16 + m_lane) * BK + quad * 8);
            #pragma unroll
            for (int n = 0; n < 4; ++n)
                bf[n] = *(const f16x8*)(Bs + (wn * 64 + n * 16 + m_lane) * BK + quad * 8);
            #pragma unroll
            for (int m = 0; m < 4; ++m)
                #pragma unroll
                for (int n = 0; n < 4; ++n)
                    acc[m][n] = __builtin_amdgcn_mfma_f32_16x16x32_f16(af[m], bf[n], acc[m][n], 0, 0, 0);
            __syncthreads();
        }

        // diag: when jt==rowblk, row tid's self-dot sits at local col tid
        const int skipc = (jt == rowblk) ? tid : -1;

        // spill C and scan, in two 64-column halves (keeps LDS at 48.5 KB)
        #pragma unroll
        for (int h = 0; h < 2; ++h) {
            if (wn == h) {
                #pragma unroll
                for (int m = 0; m < 4; ++m) {
                    const int rr = wm * 64 + m * 16 + quad * 4;
                    #pragma unroll
                    for (int n = 0; n < 4; ++n) {
                        const int cc = n * 16 + m_lane;
                        #pragma unroll
                        for (int i = 0; i < 4; ++i)
                            Cs[(rr + i) * 65 + cc] = acc[m][n][i];  // C/D: col=lane&15, row=quad*4+i
                    }
                }
            }
            __syncthreads();
            if (tid < BM) {
                #pragma unroll 4
                for (int c = 0; c < 64; ++c) {
                    const int cr = (tid + c) & 63;    // rotate start -> conflict-free
                    const float v = Cs[tid * 65 + cr];
                    if (cr + h * 64 != skipc)
                        top5_insert(v, t0, t1, t2, t3, t4);
                }
            }
            __syncthreads();
        }
    }

    if (tid < BM) {
        const int row = i0 + tid;
        float* p = part + (size_t)row * (NSPLIT * KNN) + split * KNN;
        p[0] = t0; p[1] = t1; p[2] = t2; p[3] = t3; p[4] = t4;
    }
}

// ---------------------------------------------------------------------------
// Kernel 3: merge the 8 per-split top-5 lists per row, compute the loss term,
// reduce, atomicAdd into d_out (pre-zeroed by memsetAsync).
// ---------------------------------------------------------------------------
__global__ __launch_bounds__(256) void merge_kernel(const float* __restrict__ part,
                                                    float* __restrict__ out) {
    const int row = blockIdx.x * 256 + threadIdx.x;
    const float* p = part + (size_t)row * (NSPLIT * KNN);
    float t0 = -2.f, t1 = -2.f, t2 = -2.f, t3 = -2.f, t4 = -2.f;
    #pragma unroll
    for (int k = 0; k < NSPLIT * KNN; ++k)
        top5_insert(p[k], t0, t1, t2, t3, t4);

    // unit vectors: ||xi - xj|| = sqrt(2 - 2*dot)
    float s = 0.f;
    s += sqrtf(fmaxf(2.f - 2.f * t0, 0.f));
    s += sqrtf(fmaxf(2.f - 2.f * t1, 0.f));
    s += sqrtf(fmaxf(2.f - 2.f * t2, 0.f));
    s += sqrtf(fmaxf(2.f - 2.f * t3, 0.f));
    s += sqrtf(fmaxf(2.f - 2.f * t4, 0.f));
    const float mean_rho = s * (1.f / KNN);
    float val = logf(mean_rho + EPSV);

    #pragma unroll
    for (int off = 32; off > 0; off >>= 1) val += __shfl_down(val, off, 64);
    __shared__ float red[4];
    const int lane = threadIdx.x & 63, wv = threadIdx.x >> 6;
    if (lane == 0) red[wv] = val;
    __syncthreads();
    if (threadIdx.x == 0) {
        const float blocksum = red[0] + red[1] + red[2] + red[3];
        atomicAdd(out, -blocksum / (float)NROWS);
    }
}

// ---------------------------------------------------------------------------
extern "C" void kernel_launch(void* const* d_in, const int* in_sizes, int n_in,
                              void* d_out, int out_size, void* d_ws, size_t ws_size,
                              hipStream_t stream) {
    const float* x = (const float*)d_in[0];
    float* out = (float*)d_out;
    char* ws = (char*)d_ws;

    _Float16* xnh = (_Float16*)ws;                                  // 8 MB
    float* part = (float*)(ws + (size_t)NROWS * DIM * sizeof(_Float16));  // 1.31 MB

    hipMemsetAsync(out, 0, sizeof(float), stream);  // d_out is poisoned 0xAA each call
    norm_kernel<<<NROWS, 256, 0, stream>>>(x, xnh);
    dots_top5_kernel<<<(NROWS / BM) * NSPLIT, 256, 0, stream>>>(xnh, part);
    merge_kernel<<<NROWS / 256, 256, 0, stream>>>(part, out);
}

// Round 2
// 274.628 us; speedup vs baseline: 2.0784x; 2.0784x over previous
//
#include <hip/hip_runtime.h>
#include <math.h>

// Problem constants (x: [8192, 512] fp32, K=5, eps=1e-8, scalar fp32 loss)
#define NROWS 8192
#define DIM   512
#define KNN   5
#define EPSV  1e-8f

// GEMM tiling: 128x128 block tile, BK=32, 4 waves (2x2), each wave 4x4 of 16x16x32 MFMA
#define BM 128
#define BN 128
#define BK 32
#define NSPLIT 16              // j-range splits per row-block -> 64*16 = 1024 blocks
#define JT_PER_SPLIT ((NROWS / BN) / NSPLIT)   // 4

typedef __attribute__((ext_vector_type(8))) _Float16 f16x8;
typedef __attribute__((ext_vector_type(4))) float    f32x4;

// async global->LDS, 16B per lane (LDS side must be wave-uniform base + lane*16)
__device__ __forceinline__ void gload16(const _Float16* g, _Float16* l) {
    __builtin_amdgcn_global_load_lds(
        (const __attribute__((address_space(1))) void*)g,
        (__attribute__((address_space(3))) void*)l, 16, 0, 0);
}

__device__ __forceinline__ void cmpswap(float& a, float& b) {
    const float hi = fmaxf(a, b), lo = fminf(a, b);
    a = hi; b = lo;
}

// merge two sorted-descending 5-lists -> top-5 (into a). 10 min + 15 max ops.
// identity: c[k] = max(a[k], b[k], max_{i+j=k-1} min(a[i], b[j]))
__device__ __forceinline__ void merge5(float a[KNN], const float b[KNN]) {
    const float c0 = fmaxf(a[0], b[0]);
    const float c1 = fmaxf(fmaxf(a[1], b[1]), fminf(a[0], b[0]));
    const float c2 = fmaxf(fmaxf(a[2], b[2]),
                           fmaxf(fminf(a[0], b[1]), fminf(a[1], b[0])));
    const float c3 = fmaxf(fmaxf(a[3], b[3]),
                           fmaxf(fminf(a[0], b[2]),
                                 fmaxf(fminf(a[1], b[1]), fminf(a[2], b[0]))));
    const float c4 = fmaxf(fmaxf(a[4], b[4]),
                           fmaxf(fmaxf(fminf(a[0], b[3]), fminf(a[1], b[2])),
                                 fmaxf(fminf(a[2], b[1]), fminf(a[3], b[0]))));
    a[0] = c0; a[1] = c1; a[2] = c2; a[3] = c3; a[4] = c4;
}

__device__ __forceinline__ void top5_insert(float v, float& t0, float& t1,
                                            float& t2, float& t3, float& t4) {
    if (v > t4) {
        if (v > t2) {
            if (v > t1) {
                if (v > t0) { t4 = t3; t3 = t2; t2 = t1; t1 = t0; t0 = v; }
                else        { t4 = t3; t3 = t2; t2 = t1; t1 = v; }
            } else          { t4 = t3; t3 = t2; t2 = v; }
        } else {
            if (v > t3)     { t4 = t3; t3 = v; }
            else            { t4 = v; }
        }
    }
}

// ---------------------------------------------------------------------------
// Kernel 1: row-normalize x (fp32) -> xn (f16). One block per row.
// ---------------------------------------------------------------------------
__global__ __launch_bounds__(256) void norm_kernel(const float* __restrict__ x,
                                                   _Float16* __restrict__ xnh) {
    const int row = blockIdx.x;
    const int t   = threadIdx.x;
    const float* xr = x + (size_t)row * DIM;
    float v0 = xr[t];
    float v1 = xr[t + 256];
    float s = v0 * v0 + v1 * v1;
    #pragma unroll
    for (int off = 32; off > 0; off >>= 1) s += __shfl_down(s, off, 64);
    __shared__ float wsum[4];
    __shared__ float inv_s;
    const int lane = t & 63, wv = t >> 6;
    if (lane == 0) wsum[wv] = s;
    __syncthreads();
    if (t == 0) {
        float tot = wsum[0] + wsum[1] + wsum[2] + wsum[3];
        inv_s = 1.0f / sqrtf(tot);
    }
    __syncthreads();
    const float inv = inv_s;
    _Float16* o = xnh + (size_t)row * DIM;
    o[t]       = (_Float16)(v0 * inv);
    o[t + 256] = (_Float16)(v1 * inv);
}

// ---------------------------------------------------------------------------
// Kernel 2: fused Gram-tile GEMM + in-register per-row top-5.
// Block = 256 threads (4 waves, 2x2 over a 128x128 tile). blockIdx ->
// (rowblk 0..63, split 0..15); each block scans cols [split*512, +512).
// State: lane (quad, m_lane) of each wave owns the running sorted top-5 for
// row = wm*64 + (m_lane>>2)*16 + quad*4 + (m_lane&3)  (5 VGPRs).
// Per j-tile, per (m,i): wave-uniform prune (__any vs owner's t4), else
// sort-4 + 4-step shfl_xor butterfly merge of sorted-5 lists. No C spill.
// ---------------------------------------------------------------------------
__global__ __launch_bounds__(256) void dots_top5_kernel(const _Float16* __restrict__ xnh,
                                                        float* __restrict__ part) {
    __shared__ __align__(16) _Float16 As[BM * BK];   // 8 KB
    __shared__ __align__(16) _Float16 Bs[BN * BK];   // 8 KB
    __shared__ float mbuf[2 * 64 * KNN];             // 2.5 KB cross-wave merge

    const int tid    = threadIdx.x;
    const int lane   = tid & 63;
    const int wv     = tid >> 6;
    const int wm     = wv >> 1;          // wave row half (0..1)
    const int wn     = wv & 1;           // wave col half (0..1)
    const int m_lane = lane & 15;        // MFMA: m (A) / n (B) / col (C)
    const int quad   = lane >> 4;        // MFMA: k-chunk (A,B) / row-group (C)

    const int rowblk = blockIdx.x >> 4;  // 0..63
    const int split  = blockIdx.x & 15;  // 0..15
    const int i0     = rowblk * BM;

    float t[KNN];
    #pragma unroll
    for (int k = 0; k < KNN; ++k) t[k] = -2.f;

    for (int jj = 0; jj < JT_PER_SPLIT; ++jj) {
        const int jt = split * JT_PER_SPLIT + jj;
        const int j0 = jt * BN;

        f32x4 acc[4][4];
        #pragma unroll
        for (int m = 0; m < 4; ++m)
            #pragma unroll
            for (int n = 0; n < 4; ++n)
                acc[m][n] = (f32x4){0.f, 0.f, 0.f, 0.f};

        for (int ks = 0; ks < DIM / BK; ++ks) {
            const int k0 = ks * BK;
            // stage A,B tiles via async global->LDS: seg s = tid + q*256,
            // row = s>>2, kseg = s&3; LDS side is lane-linear per wave.
            #pragma unroll
            for (int q = 0; q < 2; ++q) {
                const int s  = tid + q * 256;
                const int r  = s >> 2;
                const int kk = s & 3;
                gload16(xnh + (size_t)(i0 + r) * DIM + k0 + kk * 8, As + s * 8);
                gload16(xnh + (size_t)(j0 + r) * DIM + k0 + kk * 8, Bs + s * 8);
            }
            __syncthreads();

            f16x8 af[4], bf[4];
            #pragma unroll
            for (int m = 0; m < 4; ++m)
                af[m] = *(const f16x8*)(As + (wm * 64 + m * 16 + m_lane) * BK + quad * 8);
            #pragma unroll
            for (int n = 0; n < 4; ++n)
                bf[n] = *(const f16x8*)(Bs + (wn * 64 + n * 16 + m_lane) * BK + quad * 8);
            #pragma unroll
            for (int m = 0; m < 4; ++m)
                #pragma unroll
                for (int n = 0; n < 4; ++n)
                    acc[m][n] = __builtin_amdgcn_mfma_f32_16x16x32_f16(af[m], bf[n], acc[m][n], 0, 0, 0);
            __syncthreads();
        }

        // diagonal mask: C elem (m,n,i) is global (i0+wm*64+m*16+quad*4+i,
        // j0+wn*64+n*16+m_lane); self-dot only when jt==rowblk && wm==wn && m==n.
        const bool diag = (jt == rowblk) && (wm == wn);
        #pragma unroll
        for (int m = 0; m < 4; ++m)
            #pragma unroll
            for (int i = 0; i < 4; ++i)
                acc[m][m][i] = (diag && (quad * 4 + i) == m_lane) ? -2.f : acc[m][m][i];

        // selection: per (m,i), the 16 lanes of each quad-group hold the 64
        // cols of one row (4 vals/lane across n).
        #pragma unroll
        for (int m = 0; m < 4; ++m) {
            #pragma unroll
            for (int i = 0; i < 4; ++i) {
                const float v0 = acc[m][0][i], v1 = acc[m][1][i];
                const float v2 = acc[m][2][i], v3 = acc[m][3][i];
                const float lmax = fmaxf(fmaxf(v0, v1), fmaxf(v2, v3));
                const int owner = m * 4 + i;      // m_lane index owning this row
                const float thr = __shfl(t[4], quad * 16 + owner, 64);
                if (__any(lmax > thr)) {
                    float c[KNN];
                    c[0] = v0; c[1] = v1; c[2] = v2; c[3] = v3; c[4] = -2.f;
                    cmpswap(c[0], c[1]); cmpswap(c[2], c[3]);
                    cmpswap(c[0], c[2]); cmpswap(c[1], c[3]);
                    cmpswap(c[1], c[2]);
                    #pragma unroll
                    for (int d = 1; d < 16; d <<= 1) {
                        float b[KNN];
                        #pragma unroll
                        for (int k = 0; k < KNN; ++k) b[k] = __shfl_xor(c[k], d, 64);
                        merge5(c, b);
                    }
                    float nt[KNN];
                    #pragma unroll
                    for (int k = 0; k < KNN; ++k) nt[k] = t[k];
                    merge5(nt, c);
                    const bool is_owner = (m_lane == owner);
                    #pragma unroll
                    for (int k = 0; k < KNN; ++k) t[k] = is_owner ? nt[k] : t[k];
                }
            }
        }
    }

    // cross-wave (wn) merge: both col-half waves hold the same 64 rows.
    __syncthreads();
    const int rowlocal = (m_lane >> 2) * 16 + quad * 4 + (m_lane & 3);
    if (wn == 1) {
        #pragma unroll
        for (int k = 0; k < KNN; ++k)
            mbuf[(wm * 64 + rowlocal) * KNN + k] = t[k];
    }
    __syncthreads();
    if (wn == 0) {
        float b[KNN];
        #pragma unroll
        for (int k = 0; k < KNN; ++k) b[k] = mbuf[(wm * 64 + rowlocal) * KNN + k];
        merge5(t, b);
        const int row = i0 + wm * 64 + rowlocal;
        float* p = part + (size_t)row * (NSPLIT * KNN) + split * KNN;
        #pragma unroll
        for (int k = 0; k < KNN; ++k) p[k] = t[k];
    }
}

// ---------------------------------------------------------------------------
// Kernel 3: merge the NSPLIT per-split top-5 lists per row, loss, reduce.
// ---------------------------------------------------------------------------
__global__ __launch_bounds__(256) void merge_kernel(const float* __restrict__ part,
                                                    float* __restrict__ out) {
    const int row = blockIdx.x * 256 + threadIdx.x;
    const float* p = part + (size_t)row * (NSPLIT * KNN);
    float t0 = -2.f, t1 = -2.f, t2 = -2.f, t3 = -2.f, t4 = -2.f;
    #pragma unroll
    for (int k = 0; k < NSPLIT * KNN; ++k)
        top5_insert(p[k], t0, t1, t2, t3, t4);

    // unit vectors: ||xi - xj|| = sqrt(2 - 2*dot)
    float s = 0.f;
    s += sqrtf(fmaxf(2.f - 2.f * t0, 0.f));
    s += sqrtf(fmaxf(2.f - 2.f * t1, 0.f));
    s += sqrtf(fmaxf(2.f - 2.f * t2, 0.f));
    s += sqrtf(fmaxf(2.f - 2.f * t3, 0.f));
    s += sqrtf(fmaxf(2.f - 2.f * t4, 0.f));
    const float mean_rho = s * (1.f / KNN);
    float val = logf(mean_rho + EPSV);

    #pragma unroll
    for (int off = 32; off > 0; off >>= 1) val += __shfl_down(val, off, 64);
    __shared__ float red[4];
    const int lane = threadIdx.x & 63, wv = threadIdx.x >> 6;
    if (lane == 0) red[wv] = val;
    __syncthreads();
    if (threadIdx.x == 0) {
        const float blocksum = red[0] + red[1] + red[2] + red[3];
        atomicAdd(out, -blocksum / (float)NROWS);
    }
}

// ---------------------------------------------------------------------------
extern "C" void kernel_launch(void* const* d_in, const int* in_sizes, int n_in,
                              void* d_out, int out_size, void* d_ws, size_t ws_size,
                              hipStream_t stream) {
    const float* x = (const float*)d_in[0];
    float* out = (float*)d_out;
    char* ws = (char*)d_ws;

    _Float16* xnh = (_Float16*)ws;                                        // 8 MB
    float* part = (float*)(ws + (size_t)NROWS * DIM * sizeof(_Float16));  // 2.62 MB

    hipMemsetAsync(out, 0, sizeof(float), stream);  // d_out is poisoned 0xAA each call
    norm_kernel<<<NROWS, 256, 0, stream>>>(x, xnh);
    dots_top5_kernel<<<(NROWS / BM) * NSPLIT, 256, 0, stream>>>(xnh, part);
    merge_kernel<<<NROWS / 256, 256, 0, stream>>>(part, out);
}